// Round 6
// baseline (4500953.906 us; speedup 1.0000x reference)
//
#include <hip/hip_runtime.h>

using short8 = __attribute__((ext_vector_type(8))) short;
using f32x4  = __attribute__((ext_vector_type(4))) float;

#define NT     512
#define NBATCH 64
#define NN     1024
#define NIN    24
#define NGRP   8
#define BPG    8                        // batches per group
#define OBS_BUF_ELEMS (NGRP * BPG * NN) // 64K u16 per ping-pong buffer

// ws layout: [0,256) arrival u32[64] | [256,512) xcc u32[64]
//            [1024,1536) step flags 8 grp x 32 u16 | [4096,8192) zero region
//            [8192,...) obs 2 x [8 grp][8 rows][1024] bf16
#define POLL_CAP 100000   // escape hatch: fail loudly instead of hanging

__device__ __forceinline__ unsigned short f2bf(float x) {
  union { float f; unsigned u; } v; v.f = x;
  return (unsigned short)((v.u + 0x7FFFu + ((v.u >> 16) & 1u)) >> 16);
}

__device__ __forceinline__ f32x4 MF(short8 a, short8 b, f32x4 c) {
  return __builtin_amdgcn_mfma_f32_16x16x32_bf16(a, b, c, 0, 0, 0);
}

// obs A-fragment load: fast -> sc0 (L1-bypass, XCD-L2 read); slow -> sc0 sc1 (L3 read)
__device__ __forceinline__ short8 ld_obs(const unsigned short* p, bool fast) {
  short8 r;
  if (fast) asm volatile("global_load_dwordx4 %0, %1, off sc0"     : "=v"(r) : "v"(p));
  else      asm volatile("global_load_dwordx4 %0, %1, off sc0 sc1" : "=v"(r) : "v"(p));
  return r;
}
__device__ __forceinline__ void st_u16(unsigned short* p, unsigned v, bool fast) {
  if (fast) asm volatile("global_store_short %0, %1, off sc0"     :: "v"(p), "v"(v) : "memory");
  else      asm volatile("global_store_short %0, %1, off sc0 sc1" :: "v"(p), "v"(v) : "memory");
}
__device__ __forceinline__ unsigned ld_u16(const unsigned short* p, bool fast) {
  unsigned x;
  if (fast) asm volatile("global_load_ushort %0, %1, off sc0\n\ts_waitcnt vmcnt(0)"
                         : "=v"(x) : "v"(p) : "memory");
  else      asm volatile("global_load_ushort %0, %1, off sc0 sc1\n\ts_waitcnt vmcnt(0)"
                         : "=v"(x) : "v"(p) : "memory");
  return x;
}
__device__ __forceinline__ unsigned ld_u32_dev(const unsigned* p) {
  unsigned x;
  asm volatile("global_load_dword %0, %1, off sc0 sc1\n\ts_waitcnt vmcnt(0)"
               : "=v"(x) : "v"(p) : "memory");
  return x;
}
// u prefetch as asm so it cannot be hoisted into the counted-vmcnt pipeline
__device__ __forceinline__ f32x4 ld_f32x4(const float* p) {
  f32x4 r;
  asm volatile("global_load_dwordx4 %0, %1, off" : "=v"(r) : "v"(p));
  return r;
}
#define VMWAIT(N) do { asm volatile("s_waitcnt vmcnt(" #N ")" ::: "memory"); \
                       __builtin_amdgcn_sched_barrier(0); } while (0)

// 64 WGs x 512 thr (8 waves). Group g=bid&7: 8 WGs {g,g+8,...}; slot=bid>>3 owns
// neurons [128*slot,+128), wave w owns 16. Batches [8g,8g+8). W in VGPRs.
// Runtime XCC_ID check picks coherence point: same-XCD -> L2 (sc0), else L3 (sc0sc1).
__global__ __launch_bounds__(512, 2) void rnn_step_all(
    const float* __restrict__ u, const float* __restrict__ r0,
    const float* __restrict__ W, const float* __restrict__ Bm,
    const float* __restrict__ tau, const float* __restrict__ ds,
    float* __restrict__ out,
    unsigned* __restrict__ arr, unsigned* __restrict__ xcc_arr,
    unsigned short* __restrict__ sflags, unsigned short* __restrict__ zreg,
    unsigned short* __restrict__ obs)
{
  const int tid  = threadIdx.x;
  const int wave = tid >> 6;
  const int lane = tid & 63;
  const int bid  = blockIdx.x;
  const int g    = bid & 7;
  const int slot = bid >> 3;
  const int b0   = g * BPG;
  const int lr = lane & 15, lg = lane >> 4;
  const int i  = slot * 128 + wave * 16 + lr;   // this lane's neuron

  unsigned short* gf = sflags + g * 32;

  // ---- persistent W fragments: B[k][col] = W[i0+col][kb*32+k]*sign ----
  short8 wf[32];
#pragma unroll
  for (int kb = 0; kb < 32; ++kb) {
    const int j0 = kb * 32 + lg * 8;
    const float* wp = W + (size_t)i * NN + j0;
    f32x4 w0 = *(const f32x4*)(wp);
    f32x4 w1 = *(const f32x4*)(wp + 4);
    f32x4 s0 = *(const f32x4*)(ds + j0);
    f32x4 s1 = *(const f32x4*)(ds + j0 + 4);
    short8 f;
    f[0] = (short)f2bf(w0[0] * s0[0]); f[1] = (short)f2bf(w0[1] * s0[1]);
    f[2] = (short)f2bf(w0[2] * s0[2]); f[3] = (short)f2bf(w0[3] * s0[3]);
    f[4] = (short)f2bf(w1[0] * s1[0]); f[5] = (short)f2bf(w1[1] * s1[1]);
    f[6] = (short)f2bf(w1[2] * s1[2]); f[7] = (short)f2bf(w1[3] * s1[3]);
    wf[kb] = f;
  }
  short8 bin;
#pragma unroll
  for (int e = 0; e < 8; ++e) {
    const int m = lg * 8 + e;
    bin[e] = (short)f2bf(m < NIN ? Bm[(size_t)i * NIN + m] : 0.0f);
  }
  const float itau = 1.0f / tau[i];

  unsigned short* owbuf0 = obs + g * BPG * NN;
  unsigned short* owbuf1 = owbuf0 + OBS_BUF_ELEMS;

  // ---- init r; publish obs buf0 (device-scope: path not yet known) ----
  f32x4 r = {0.f, 0.f, 0.f, 0.f};
  if (lg < 2) {
#pragma unroll
    for (int q = 0; q < 4; ++q) {
      const int row = lg * 4 + q;
      r[q] = r0[(size_t)(b0 + row) * NN + i];
      st_u16(owbuf0 + row * NN + i, f2bf(r[q] > 0.0f ? r[q] : 0.0f), false);
    }
  }
  asm volatile("s_waitcnt vmcnt(0)" ::: "memory");
  __syncthreads();

  // ---- publish XCC_ID + arrival (release-ordered), grid init barrier ----
  unsigned xcc;
  asm volatile("s_getreg_b32 %0, hwreg(HW_REG_XCC_ID)" : "=s"(xcc));
  if (tid == 0) {
    asm volatile("global_store_dword %0, %1, off sc0 sc1\n\ts_waitcnt vmcnt(0)"
                 :: "v"(&xcc_arr[bid]), "v"(xcc) : "memory");
    asm volatile("global_store_dword %0, %1, off sc0 sc1"
                 :: "v"(&arr[bid]), "v"(1u) : "memory");
  }
  const float* up_base = u + (size_t)(b0 + lr) * NT * NIN;
  f32x4 up0 = {0.f,0.f,0.f,0.f}, up1 = {0.f,0.f,0.f,0.f};
  if (lr < 8 && lg < 3) {           // plain loads; drained by the poll's vmcnt(0)
    up0 = *(const f32x4*)(up_base + lg * 8);
    up1 = *(const f32x4*)(up_base + lg * 8 + 4);
  }
  if (wave == 0) {
    int guard = 0;
    for (;;) {
      unsigned x = ld_u32_dev(&arr[lane]);
      if (__all((int)(x >= 1u))) break;
      if (++guard > POLL_CAP) break;
      __builtin_amdgcn_s_sleep(1);
    }
  }
  __syncthreads();
  __builtin_amdgcn_sched_barrier(0);

  // ---- group co-location check (uniform across group) ----
  unsigned myx = ld_u32_dev(&xcc_arr[g + 8 * (lane & 7)]);
  unsigned x0  = (unsigned)__builtin_amdgcn_readfirstlane((int)myx);
  const bool fast = __all((int)(myx == x0)) != 0;

  // per-lane A base (rows >= 8 of the 16x16 A tile read the zero region)
  const unsigned short* ab0;
  if (lr < 8) ab0 = owbuf0 + lr * NN + lg * 8;
  else        ab0 = zreg + lg * 8;
  const unsigned short* ab1 = (lr < 8) ? ab0 + OBS_BUF_ELEMS : ab0;

  for (int t = 0; t < NT; ++t) {
    const unsigned short* ab = (t & 1) ? ab1 : ab0;
    unsigned short*       ow = (t & 1) ? owbuf0 : owbuf1;

    f32x4 acc  = {0.f, 0.f, 0.f, 0.f};
    f32x4 acc1 = {0.f, 0.f, 0.f, 0.f};

    // input term: A[row=lr][m] = u[b0+lr][t][m], zero-padded
    short8 ua;
    ua[0] = (short)f2bf(up0[0]); ua[1] = (short)f2bf(up0[1]);
    ua[2] = (short)f2bf(up0[2]); ua[3] = (short)f2bf(up0[3]);
    ua[4] = (short)f2bf(up1[0]); ua[5] = (short)f2bf(up1[1]);
    ua[6] = (short)f2bf(up1[2]); ua[7] = (short)f2bf(up1[3]);
    if (lr >= 8 || lg >= 3) ua = short8{0,0,0,0,0,0,0,0};
    acc = MF(ua, bin, acc);

    // recurrent GEMM: counted-vmcnt 3-buffer pipeline, chunks of 4 kb (4 loads)
    short8 B[3][4];
#pragma unroll
    for (int j = 0; j < 4; ++j) B[0][j] = ld_obs(ab + j * 32, fast);
#pragma unroll
    for (int j = 0; j < 4; ++j) B[1][j] = ld_obs(ab + 128 + j * 32, fast);
#pragma unroll
    for (int c = 0; c < 8; ++c) {
      if (c < 6) {
#pragma unroll
        for (int j = 0; j < 4; ++j)
          B[(c + 2) % 3][j] = ld_obs(ab + (c + 2) * 128 + j * 32, fast);
      }
      if (c < 6)      VMWAIT(8);
      else if (c == 6) VMWAIT(4);
      else             VMWAIT(0);
#pragma unroll
      for (int j = 0; j < 4; ++j) {
        if (j & 1) acc1 = MF(B[c % 3][j], wf[c * 4 + j], acc1);
        else       acc  = MF(B[c % 3][j], wf[c * 4 + j], acc);
      }
    }

    // state update
    f32x4 rv;
#pragma unroll
    for (int q = 0; q < 4; ++q) {
      const float pre = acc[q] + acc1[q];
      const float act = 60.0f / (1.0f + expf(8.4f - 0.28f * pre));  // 30*(1+tanh(.14x-4.2))
      rv[q] = r[q] + (0.1f * (act - r[q])) * itau;
      r[q]  = rv[q];
    }

    if (t != NT - 1) {
      if (lg < 2) {
#pragma unroll
        for (int q = 0; q < 4; ++q)
          st_u16(ow + (lg * 4 + q) * NN + i, f2bf(rv[q] > 0.0f ? rv[q] : 0.0f), fast);
      }
      asm volatile("s_waitcnt vmcnt(0)" ::: "memory");
      __syncthreads();
      if (tid == 0) st_u16(gf + slot, (unsigned)(t + 1), fast);

      // off-critical-path: u prefetch (asm, can't leak into pipeline) + out stores
      if (lr < 8 && lg < 3) {
        const float* up = up_base + (t + 1) * NIN + lg * 8;
        up0 = ld_f32x4(up);
        up1 = ld_f32x4(up + 4);
      }
      if (lg < 2) {
#pragma unroll
        for (int q = 0; q < 4; ++q)
          __builtin_nontemporal_store(rv[q],
              &out[((size_t)(b0 + lg * 4 + q) * NT + t) * NN + i]);
      }
      const unsigned tgt = (unsigned)(t + 1);
      if (wave == 0) {
        int guard = 0;
        for (;;) {
          unsigned x = ld_u16(gf + (lane & 7), fast);
          if (__all((int)(x >= tgt))) break;
          if (++guard > POLL_CAP) break;
          __builtin_amdgcn_s_sleep(1);
        }
      }
      __syncthreads();
      __builtin_amdgcn_sched_barrier(0);
    } else {
      if (lg < 2) {
#pragma unroll
        for (int q = 0; q < 4; ++q)
          __builtin_nontemporal_store(rv[q],
              &out[((size_t)(b0 + lg * 4 + q) * NT + t) * NN + i]);
      }
    }
  }

  // r_final
  if (lg < 2) {
#pragma unroll
    for (int q = 0; q < 4; ++q)
      out[(size_t)NBATCH * NT * NN + (size_t)(b0 + lg * 4 + q) * NN + i] = r[q];
  }
}

extern "C" void kernel_launch(void* const* d_in, const int* in_sizes, int n_in,
                              void* d_out, int out_size, void* d_ws, size_t ws_size,
                              hipStream_t stream) {
  const float* u   = (const float*)d_in[0];
  const float* r0  = (const float*)d_in[1];
  const float* W   = (const float*)d_in[2];
  const float* Bm  = (const float*)d_in[3];
  const float* tau = (const float*)d_in[4];
  const float* ds  = (const float*)d_in[5];
  float* out = (float*)d_out;

  unsigned*       arr     = (unsigned*)d_ws;
  unsigned*       xcc_arr = (unsigned*)((char*)d_ws + 256);
  unsigned short* sflags  = (unsigned short*)((char*)d_ws + 1024);
  unsigned short* zreg    = (unsigned short*)((char*)d_ws + 4096);
  unsigned short* obs     = (unsigned short*)((char*)d_ws + 8192);

  // zero flags + zero-region every call (incl. graph replays -> deterministic)
  hipMemsetAsync(d_ws, 0, 8192, stream);

  rnn_step_all<<<dim3(64), dim3(512), 0, stream>>>(u, r0, W, Bm, tau, ds, out,
                                                   arr, xcc_arr, sflags, zreg, obs);
}

// Round 7
// 3122.805 us; speedup vs baseline: 1441.3178x; 1441.3178x over previous
//
#include <hip/hip_runtime.h>

using short8 = __attribute__((ext_vector_type(8))) short;
using f32x4  = __attribute__((ext_vector_type(4))) float;

#define NT     512
#define NBATCH 64
#define NN     1024
#define NIN    24
#define NGRP   8
#define BPG    8                        // batches per group
#define OBS_BUF_ELEMS (NGRP * BPG * NN) // 64K u16 per ping-pong buffer
#define SCOPE_AGENT __HIP_MEMORY_SCOPE_AGENT
#define POLL_CAP 20000  // fast-poll guard; falls back to proven agent-atomic poll

// ws: [0,256) arr u32[64] | [256,512) xcc u32[64] | [1024,1536) flags 8x32 u16
//     [4096,8192) zero region | [8192,+256KB) obs 2 x [8 grp][8 rows][1024] bf16

__device__ __forceinline__ unsigned short f2bf(float x) {
  union { float f; unsigned u; } v; v.f = x;
  return (unsigned short)((v.u + 0x7FFFu + ((v.u >> 16) & 1u)) >> 16);
}
__device__ __forceinline__ f32x4 MF(short8 a, short8 b, f32x4 c) {
  return __builtin_amdgcn_mfma_f32_16x16x32_bf16(a, b, c, 0, 0, 0);
}

// 64 WGs x 512 thr (8 waves). Group g=bid&7 (verified co-located on one XCD at
// runtime via XCC_ID): 8 WGs {g,g+8,...}; slot=bid>>3 owns neurons [128*slot,+128),
// wave w owns 16. Batches [8g,8g+8). W fragments persistent in VGPRs.
// Fast path: obs exchange through the XCD's shared L2 (plain stores/loads);
// poll = buffer_inv + plain load (L1 invalidate each iter — gfx950 sc0 loads do
// NOT bypass L1, the R4/R5 failure). Slow path: R3-proven agent atomics.
__global__ __launch_bounds__(512, 2) void rnn_step_all(
    const float* __restrict__ u, const float* __restrict__ r0,
    const float* __restrict__ W, const float* __restrict__ Bm,
    const float* __restrict__ tau, const float* __restrict__ ds,
    float* __restrict__ out,
    unsigned* __restrict__ arr, unsigned* __restrict__ xcc_arr,
    unsigned short* __restrict__ sflags, unsigned short* __restrict__ zreg,
    unsigned short* __restrict__ obs)
{
  const int tid  = threadIdx.x;
  const int wave = tid >> 6;
  const int lane = tid & 63;
  const int bid  = blockIdx.x;
  const int g    = bid & 7;
  const int slot = bid >> 3;
  const int b0   = g * BPG;
  const int lr = lane & 15, lg = lane >> 4;
  const int i  = slot * 128 + wave * 16 + lr;   // this lane's neuron

  unsigned short* gf = sflags + g * 32;

  // ---- persistent W fragments: B[k][col] = W[i0+col][kb*32+k]*sign ----
  short8 wf[32];
#pragma unroll
  for (int kb = 0; kb < 32; ++kb) {
    const int j0 = kb * 32 + lg * 8;
    const float* wp = W + (size_t)i * NN + j0;
    f32x4 w0 = *(const f32x4*)(wp);
    f32x4 w1 = *(const f32x4*)(wp + 4);
    f32x4 s0 = *(const f32x4*)(ds + j0);
    f32x4 s1 = *(const f32x4*)(ds + j0 + 4);
    short8 f;
    f[0] = (short)f2bf(w0[0] * s0[0]); f[1] = (short)f2bf(w0[1] * s0[1]);
    f[2] = (short)f2bf(w0[2] * s0[2]); f[3] = (short)f2bf(w0[3] * s0[3]);
    f[4] = (short)f2bf(w1[0] * s1[0]); f[5] = (short)f2bf(w1[1] * s1[1]);
    f[6] = (short)f2bf(w1[2] * s1[2]); f[7] = (short)f2bf(w1[3] * s1[3]);
    wf[kb] = f;
  }
  short8 bin;
#pragma unroll
  for (int e = 0; e < 8; ++e) {
    const int m = lg * 8 + e;
    bin[e] = (short)f2bf(m < NIN ? Bm[(size_t)i * NIN + m] : 0.0f);
  }
  const float itau = 1.0f / tau[i];

  unsigned short* owbuf0 = obs + g * BPG * NN;
  unsigned short* owbuf1 = owbuf0 + OBS_BUF_ELEMS;

  // ---- init r; publish obs buf0 agent-scope (path not yet known) ----
  f32x4 r = {0.f, 0.f, 0.f, 0.f};
  if (lg < 2) {
#pragma unroll
    for (int q = 0; q < 4; ++q) {
      const int row = lg * 4 + q;
      r[q] = r0[(size_t)(b0 + row) * NN + i];
      __hip_atomic_store(&owbuf0[row * NN + i], f2bf(r[q] > 0.0f ? r[q] : 0.0f),
                         __ATOMIC_RELAXED, SCOPE_AGENT);
    }
  }
  asm volatile("s_waitcnt vmcnt(0)" ::: "memory");
  __syncthreads();

  // ---- publish XCC_ID + arrival, grid init barrier (proven agent atomics) ----
  unsigned xcc;
  asm volatile("s_getreg_b32 %0, hwreg(HW_REG_XCC_ID)" : "=s"(xcc));
  if (tid == 0) {
    __hip_atomic_store(&xcc_arr[bid], xcc, __ATOMIC_RELAXED, SCOPE_AGENT);
    __hip_atomic_store(&arr[bid], 1u, __ATOMIC_RELEASE, SCOPE_AGENT);
  }

  const float* up_base = u + (size_t)(b0 + lr) * NT * NIN;
  f32x4 up0 = {0.f,0.f,0.f,0.f}, up1 = {0.f,0.f,0.f,0.f};
  if (lr < 8 && lg < 3) {
    up0 = *(const f32x4*)(up_base + lg * 8);
    up1 = *(const f32x4*)(up_base + lg * 8 + 4);
  }

  if (wave == 0) {
    for (;;) {
      unsigned x = __hip_atomic_load(&arr[lane], __ATOMIC_RELAXED, SCOPE_AGENT);
      if (__all((int)(x >= 1u))) break;
      __builtin_amdgcn_s_sleep(1);
    }
  }
  __syncthreads();
  __builtin_amdgcn_fence(__ATOMIC_ACQUIRE, "agent");

  // ---- group co-location check (uniform across the group) ----
  unsigned myx = __hip_atomic_load(&xcc_arr[g + 8 * (lane & 7)],
                                   __ATOMIC_RELAXED, SCOPE_AGENT);
  unsigned x0  = (unsigned)__builtin_amdgcn_readfirstlane((int)myx);
  const bool fast = __all((int)(myx == x0)) != 0;

  // per-lane A base: rows >= 8 of the 16x16 A tile read the zero region
  const unsigned short* ab0 = (lr < 8) ? owbuf0 + lr * NN + lg * 8 : zreg + lg * 8;
  const unsigned short* ab1 = (lr < 8) ? ab0 + OBS_BUF_ELEMS : ab0;

  for (int t = 0; t < NT; ++t) {
    const unsigned short* ab = (t & 1) ? ab1 : ab0;
    unsigned short*       ow = (t & 1) ? owbuf0 : owbuf1;

    f32x4 acc  = {0.f, 0.f, 0.f, 0.f};
    f32x4 acc1 = {0.f, 0.f, 0.f, 0.f};

    // input term: A[row=lr][m] = u[b0+lr][t][m], zero-padded
    short8 ua;
    ua[0] = (short)f2bf(up0[0]); ua[1] = (short)f2bf(up0[1]);
    ua[2] = (short)f2bf(up0[2]); ua[3] = (short)f2bf(up0[3]);
    ua[4] = (short)f2bf(up1[0]); ua[5] = (short)f2bf(up1[1]);
    ua[6] = (short)f2bf(up1[2]); ua[7] = (short)f2bf(up1[3]);
    if (lr >= 8 || lg >= 3) ua = short8{0,0,0,0,0,0,0,0};
    acc = MF(ua, bin, acc);

    // recurrent GEMM: plain cacheable loads (L1 shared by all 8 waves of the CU)
#pragma unroll
    for (int kb = 0; kb < 32; kb += 2) {
      short8 a0 = *(const short8*)(ab + kb * 32);
      short8 a1 = *(const short8*)(ab + kb * 32 + 32);
      acc  = MF(a0, wf[kb],     acc);
      acc1 = MF(a1, wf[kb + 1], acc1);
    }

    // state update
    f32x4 rv;
#pragma unroll
    for (int q = 0; q < 4; ++q) {
      const float pre = acc[q] + acc1[q];
      const float act = 60.0f / (1.0f + expf(8.4f - 0.28f * pre)); // 30*(1+tanh(.14x-4.2))
      rv[q] = r[q] + (0.1f * (act - r[q])) * itau;
      r[q]  = rv[q];
    }

    if (t != NT - 1) {
      // publish obs; release: vmcnt(0) -> barrier -> one flag store
      if (fast) {
        if (lg < 2) {
#pragma unroll
          for (int q = 0; q < 4; ++q)
            ow[(lg * 4 + q) * NN + i] = f2bf(rv[q] > 0.0f ? rv[q] : 0.0f);
        }
      } else {
        if (lg < 2) {
#pragma unroll
          for (int q = 0; q < 4; ++q)
            __hip_atomic_store(&ow[(lg * 4 + q) * NN + i],
                               f2bf(rv[q] > 0.0f ? rv[q] : 0.0f),
                               __ATOMIC_RELAXED, SCOPE_AGENT);
        }
      }
      asm volatile("s_waitcnt vmcnt(0)" ::: "memory");
      __syncthreads();
      if (tid == 0) {
        if (fast) *(volatile unsigned short*)&gf[slot] = (unsigned short)(t + 1);
        else      __hip_atomic_store(&gf[slot], (unsigned short)(t + 1),
                                     __ATOMIC_RELAXED, SCOPE_AGENT);
      }

      // off-critical-path: u prefetch + out stores overlap the poll
      if (lr < 8 && lg < 3) {
        const float* up = up_base + (t + 1) * NIN + lg * 8;
        up0 = *(const f32x4*)(up);
        up1 = *(const f32x4*)(up + 4);
      }
      if (lg < 2) {
#pragma unroll
        for (int q = 0; q < 4; ++q)
          __builtin_nontemporal_store(rv[q],
              &out[((size_t)(b0 + lg * 4 + q) * NT + t) * NN + i]);
      }

      const unsigned tgt = (unsigned)(t + 1);
      if (wave == 0) {
        if (fast) {
          int guard = 0;
          for (;;) {
            asm volatile("buffer_inv" ::: "memory");   // L1 invalidate -> read L2 fresh
            unsigned x = *(volatile const unsigned short*)(gf + (lane & 7));
            if (__all((int)(x >= tgt))) break;
            if (++guard > POLL_CAP) {   // proven-correct fallback, never hang
              unsigned y;
              do {
                y = __hip_atomic_load(&gf[lane & 7], __ATOMIC_RELAXED, SCOPE_AGENT);
              } while (!__all((int)(y >= tgt)));
              asm volatile("buffer_inv" ::: "memory");
              break;
            }
          }
        } else {
          for (;;) {
            unsigned x = __hip_atomic_load(&gf[lane & 7], __ATOMIC_RELAXED, SCOPE_AGENT);
            if (__all((int)(x >= tgt))) break;
            __builtin_amdgcn_s_sleep(1);
          }
        }
      }
      __syncthreads();
      if (!fast) __builtin_amdgcn_fence(__ATOMIC_ACQUIRE, "agent");
    } else {
      if (lg < 2) {
#pragma unroll
        for (int q = 0; q < 4; ++q)
          __builtin_nontemporal_store(rv[q],
              &out[((size_t)(b0 + lg * 4 + q) * NT + t) * NN + i]);
      }
    }
  }

  // r_final
  if (lg < 2) {
#pragma unroll
    for (int q = 0; q < 4; ++q)
      out[(size_t)NBATCH * NT * NN + (size_t)(b0 + lg * 4 + q) * NN + i] = r[q];
  }
}

extern "C" void kernel_launch(void* const* d_in, const int* in_sizes, int n_in,
                              void* d_out, int out_size, void* d_ws, size_t ws_size,
                              hipStream_t stream) {
  const float* u   = (const float*)d_in[0];
  const float* r0  = (const float*)d_in[1];
  const float* W   = (const float*)d_in[2];
  const float* Bm  = (const float*)d_in[3];
  const float* tau = (const float*)d_in[4];
  const float* ds  = (const float*)d_in[5];
  float* out = (float*)d_out;

  unsigned*       arr     = (unsigned*)d_ws;
  unsigned*       xcc_arr = (unsigned*)((char*)d_ws + 256);
  unsigned short* sflags  = (unsigned short*)((char*)d_ws + 1024);
  unsigned short* zreg    = (unsigned short*)((char*)d_ws + 4096);
  unsigned short* obs     = (unsigned short*)((char*)d_ws + 8192);

  // zero arr/xcc/flags/zero-region every call (incl. graph replays)
  hipMemsetAsync(d_ws, 0, 8192, stream);

  rnn_step_all<<<dim3(64), dim3(512), 0, stream>>>(u, r0, W, Bm, tau, ds, out,
                                                   arr, xcc_arr, sflags, zreg, obs);
}

// Round 8
// 3109.980 us; speedup vs baseline: 1447.2614x; 1.0041x over previous
//
#include <hip/hip_runtime.h>

using short8 = __attribute__((ext_vector_type(8))) short;
using f32x4  = __attribute__((ext_vector_type(4))) float;

#define NT     512
#define NBATCH 64
#define NN     1024
#define NIN    24
#define NGRP   8
#define BPG    8                        // batches per group
#define OBS_BUF_ELEMS (NGRP * BPG * NN) // 64K u16 per ping-pong buffer
#define SCOPE_AGENT __HIP_MEMORY_SCOPE_AGENT
#define POLL_CAP 20000  // fast-poll guard; falls back to proven agent-atomic poll

// ws: [0,256) arr u32[64] | [256,512) xcc u32[64] | [1024,1536) flags 8x32 u16
//     [4096,8192) zero region | [8192,+256KB) obs 2 x [8 grp][8 rows][1024] bf16

__device__ __forceinline__ unsigned short f2bf(float x) {
  union { float f; unsigned u; } v; v.f = x;
  return (unsigned short)((v.u + 0x7FFFu + ((v.u >> 16) & 1u)) >> 16);
}
__device__ __forceinline__ f32x4 MF(short8 a, short8 b, f32x4 c) {
  return __builtin_amdgcn_mfma_f32_16x16x32_bf16(a, b, c, 0, 0, 0);
}

// 64 WGs x 512 thr (8 waves). Blocks publish their XCC_ID, then self-organize:
// rank by (xcc, bid) -> group = rank/8 (8 blocks, same XCD under any balanced
// placement), slot = rank%8 owns neurons [128*slot,+128). Group g owns batches
// [8g,8g+8). W fragments persistent in VGPRs; full K=1024 per wave per step.
// Fast path (group co-located): obs exchange through the XCD's shared L2
// (plain stores/loads); poll = buffer_inv + plain load each iter (gfx950 sc0
// loads do NOT bypass L1 - the R4/R5 failure). Slow path: R3-proven agent
// atomics through L3. Per-group choice, correct either way.
__global__ __launch_bounds__(512, 2) void rnn_step_all(
    const float* __restrict__ u, const float* __restrict__ r0,
    const float* __restrict__ W, const float* __restrict__ Bm,
    const float* __restrict__ tau, const float* __restrict__ ds,
    float* __restrict__ out,
    unsigned* __restrict__ arr, unsigned* __restrict__ xcc_arr,
    unsigned short* __restrict__ sflags, unsigned short* __restrict__ zreg,
    unsigned short* __restrict__ obs)
{
  const int tid  = threadIdx.x;
  const int wave = tid >> 6;
  const int lane = tid & 63;
  const int bid  = blockIdx.x;
  const int lr = lane & 15, lg = lane >> 4;

  // ---- publish my XCD + arrival; grid init barrier (proven agent atomics) ----
  unsigned myxcc;
  asm volatile("s_getreg_b32 %0, hwreg(HW_REG_XCC_ID)" : "=s"(myxcc));
  if (tid == 0) {
    __hip_atomic_store(&xcc_arr[bid], myxcc, __ATOMIC_RELAXED, SCOPE_AGENT);
    __hip_atomic_store(&arr[bid], 1u, __ATOMIC_RELEASE, SCOPE_AGENT);
  }
  if (wave == 0) {
    for (;;) {
      unsigned x = __hip_atomic_load(&arr[lane], __ATOMIC_RELAXED, SCOPE_AGENT);
      if (__all((int)(x >= 1u))) break;
      __builtin_amdgcn_s_sleep(1);
    }
  }
  __syncthreads();
  __builtin_amdgcn_fence(__ATOMIC_ACQUIRE, "agent");

  // ---- self-organize: rank blocks by (xcc, bid); group = rank/8, slot = rank%8 ----
  unsigned xj = __hip_atomic_load(&xcc_arr[lane], __ATOMIC_RELAXED, SCOPE_AGENT);
  const long long keyj = ((long long)xj << 8) | (long long)lane;
  int rank_j = 0;
#pragma unroll
  for (int k = 0; k < 64; ++k)
    rank_j += (int)(__shfl(keyj, k) < keyj);
  const int myrank = __shfl(rank_j, bid);       // rank of MY block (lane 'bid' holds it)
  const int g    = myrank >> 3;                 // batch group
  const int slot = myrank & 7;                  // neuron slice
  const bool ingrp = (rank_j >> 3) == g;        // lane's block in my group?
  const bool fast  =
      (__popcll(__ballot(ingrp && (xj == myxcc))) == 8);  // all 8 on my XCD

  const int b0 = g * BPG;
  const int i  = slot * 128 + wave * 16 + lr;   // this lane's neuron

  unsigned short* gf = sflags + g * 32;

  // ---- persistent W fragments: B[k][col] = W[i0+col][kb*32+k]*sign ----
  short8 wf[32];
#pragma unroll
  for (int kb = 0; kb < 32; ++kb) {
    const int j0 = kb * 32 + lg * 8;
    const float* wp = W + (size_t)i * NN + j0;
    f32x4 w0 = *(const f32x4*)(wp);
    f32x4 w1 = *(const f32x4*)(wp + 4);
    f32x4 s0 = *(const f32x4*)(ds + j0);
    f32x4 s1 = *(const f32x4*)(ds + j0 + 4);
    short8 f;
    f[0] = (short)f2bf(w0[0] * s0[0]); f[1] = (short)f2bf(w0[1] * s0[1]);
    f[2] = (short)f2bf(w0[2] * s0[2]); f[3] = (short)f2bf(w0[3] * s0[3]);
    f[4] = (short)f2bf(w1[0] * s1[0]); f[5] = (short)f2bf(w1[1] * s1[1]);
    f[6] = (short)f2bf(w1[2] * s1[2]); f[7] = (short)f2bf(w1[3] * s1[3]);
    wf[kb] = f;
  }
  short8 bin;
#pragma unroll
  for (int e = 0; e < 8; ++e) {
    const int m = lg * 8 + e;
    bin[e] = (short)f2bf(m < NIN ? Bm[(size_t)i * NIN + m] : 0.0f);
  }
  const float itau = 1.0f / tau[i];

  unsigned short* owbuf0 = obs + g * BPG * NN;
  unsigned short* owbuf1 = owbuf0 + OBS_BUF_ELEMS;

  // ---- init r; publish obs buf0 (agent scope), group barrier epoch 1 ----
  f32x4 r = {0.f, 0.f, 0.f, 0.f};
  if (lg < 2) {
#pragma unroll
    for (int q = 0; q < 4; ++q) {
      const int row = lg * 4 + q;
      r[q] = r0[(size_t)(b0 + row) * NN + i];
      __hip_atomic_store(&owbuf0[row * NN + i], f2bf(r[q] > 0.0f ? r[q] : 0.0f),
                         __ATOMIC_RELAXED, SCOPE_AGENT);
    }
  }
  asm volatile("s_waitcnt vmcnt(0)" ::: "memory");
  __syncthreads();
  if (tid == 0)
    __hip_atomic_store(&gf[slot], (unsigned short)1, __ATOMIC_RELAXED, SCOPE_AGENT);

  const float* up_base = u + (size_t)(b0 + lr) * NT * NIN;
  f32x4 up0 = {0.f,0.f,0.f,0.f}, up1 = {0.f,0.f,0.f,0.f};
  if (lr < 8 && lg < 3) {
    up0 = *(const f32x4*)(up_base + lg * 8);
    up1 = *(const f32x4*)(up_base + lg * 8 + 4);
  }
  if (wave == 0) {
    for (;;) {
      unsigned x = __hip_atomic_load(&gf[lane & 7], __ATOMIC_RELAXED, SCOPE_AGENT);
      if (__all((int)(x >= 1u))) break;
      __builtin_amdgcn_s_sleep(1);
    }
  }
  __syncthreads();
  __builtin_amdgcn_fence(__ATOMIC_ACQUIRE, "agent");

  // per-lane A base: rows >= 8 of the 16x16 A tile read the zero region
  const unsigned short* ab0 = (lr < 8) ? owbuf0 + lr * NN + lg * 8 : zreg + lg * 8;
  const unsigned short* ab1 = (lr < 8) ? ab0 + OBS_BUF_ELEMS : ab0;

  for (int t = 0; t < NT; ++t) {
    const unsigned short* ab = (t & 1) ? ab1 : ab0;
    unsigned short*       ow = (t & 1) ? owbuf0 : owbuf1;

    f32x4 acc  = {0.f, 0.f, 0.f, 0.f};
    f32x4 acc1 = {0.f, 0.f, 0.f, 0.f};

    // input term: A[row=lr][m] = u[b0+lr][t][m], zero-padded
    short8 ua;
    ua[0] = (short)f2bf(up0[0]); ua[1] = (short)f2bf(up0[1]);
    ua[2] = (short)f2bf(up0[2]); ua[3] = (short)f2bf(up0[3]);
    ua[4] = (short)f2bf(up1[0]); ua[5] = (short)f2bf(up1[1]);
    ua[6] = (short)f2bf(up1[2]); ua[7] = (short)f2bf(up1[3]);
    if (lr >= 8 || lg >= 3) ua = short8{0,0,0,0,0,0,0,0};
    acc = MF(ua, bin, acc);

    // recurrent GEMM: plain cacheable loads (L1 shared by the CU's 8 waves;
    // freshness guaranteed by the poll's buffer_inv on the successful iter)
#pragma unroll
    for (int kb = 0; kb < 32; kb += 2) {
      short8 a0 = *(const short8*)(ab + kb * 32);
      short8 a1 = *(const short8*)(ab + kb * 32 + 32);
      acc  = MF(a0, wf[kb],     acc);
      acc1 = MF(a1, wf[kb + 1], acc1);
    }

    // state update
    f32x4 rv;
#pragma unroll
    for (int q = 0; q < 4; ++q) {
      const float pre = acc[q] + acc1[q];
      const float act = 60.0f / (1.0f + expf(8.4f - 0.28f * pre)); // 30*(1+tanh(.14x-4.2))
      rv[q] = r[q] + (0.1f * (act - r[q])) * itau;
      r[q]  = rv[q];
    }

    if (t != NT - 1) {
      // publish obs; release: vmcnt(0) -> barrier -> one flag store (epoch t+2)
      if (fast) {
        if (lg < 2) {
#pragma unroll
          for (int q = 0; q < 4; ++q)
            ow[(lg * 4 + q) * NN + i] = f2bf(rv[q] > 0.0f ? rv[q] : 0.0f);
        }
      } else {
        if (lg < 2) {
#pragma unroll
          for (int q = 0; q < 4; ++q)
            __hip_atomic_store(&ow[(lg * 4 + q) * NN + i],
                               f2bf(rv[q] > 0.0f ? rv[q] : 0.0f),
                               __ATOMIC_RELAXED, SCOPE_AGENT);
        }
      }
      asm volatile("s_waitcnt vmcnt(0)" ::: "memory");
      __syncthreads();
      if (tid == 0) {
        if (fast) *(volatile unsigned short*)&gf[slot] = (unsigned short)(t + 2);
        else      __hip_atomic_store(&gf[slot], (unsigned short)(t + 2),
                                     __ATOMIC_RELAXED, SCOPE_AGENT);
      }

      // off-critical-path: u prefetch + out stores overlap the poll
      if (lr < 8 && lg < 3) {
        const float* up = up_base + (t + 1) * NIN + lg * 8;
        up0 = *(const f32x4*)(up);
        up1 = *(const f32x4*)(up + 4);
      }
      if (lg < 2) {
#pragma unroll
        for (int q = 0; q < 4; ++q)
          __builtin_nontemporal_store(rv[q],
              &out[((size_t)(b0 + lg * 4 + q) * NT + t) * NN + i]);
      }

      const unsigned tgt = (unsigned)(t + 2);
      if (wave == 0) {
        if (fast) {
          int guard = 0;
          for (;;) {
            asm volatile("buffer_inv" ::: "memory");   // L1 inv -> read L2 fresh
            unsigned x = *(volatile const unsigned short*)(gf + (lane & 7));
            if (__all((int)(x >= tgt))) break;
            if (++guard > POLL_CAP) {   // proven-correct fallback, never hang
              unsigned y;
              do {
                y = __hip_atomic_load(&gf[lane & 7], __ATOMIC_RELAXED, SCOPE_AGENT);
              } while (!__all((int)(y >= tgt)));
              asm volatile("buffer_inv" ::: "memory");
              break;
            }
          }
        } else {
          for (;;) {
            unsigned x = __hip_atomic_load(&gf[lane & 7], __ATOMIC_RELAXED, SCOPE_AGENT);
            if (__all((int)(x >= tgt))) break;
            __builtin_amdgcn_s_sleep(1);
          }
        }
      }
      __syncthreads();
      if (!fast) __builtin_amdgcn_fence(__ATOMIC_ACQUIRE, "agent");
    } else {
      if (lg < 2) {
#pragma unroll
        for (int q = 0; q < 4; ++q)
          __builtin_nontemporal_store(rv[q],
              &out[((size_t)(b0 + lg * 4 + q) * NT + t) * NN + i]);
      }
    }
  }

  // r_final
  if (lg < 2) {
#pragma unroll
    for (int q = 0; q < 4; ++q)
      out[(size_t)NBATCH * NT * NN + (size_t)(b0 + lg * 4 + q) * NN + i] = r[q];
  }
}

extern "C" void kernel_launch(void* const* d_in, const int* in_sizes, int n_in,
                              void* d_out, int out_size, void* d_ws, size_t ws_size,
                              hipStream_t stream) {
  const float* u   = (const float*)d_in[0];
  const float* r0  = (const float*)d_in[1];
  const float* W   = (const float*)d_in[2];
  const float* Bm  = (const float*)d_in[3];
  const float* tau = (const float*)d_in[4];
  const float* ds  = (const float*)d_in[5];
  float* out = (float*)d_out;

  unsigned*       arr     = (unsigned*)d_ws;
  unsigned*       xcc_arr = (unsigned*)((char*)d_ws + 256);
  unsigned short* sflags  = (unsigned short*)((char*)d_ws + 1024);
  unsigned short* zreg    = (unsigned short*)((char*)d_ws + 4096);
  unsigned short* obs     = (unsigned short*)((char*)d_ws + 8192);

  // zero arr/xcc/flags/zero-region every call (incl. graph replays)
  hipMemsetAsync(d_ws, 0, 8192, stream);

  rnn_step_all<<<dim3(64), dim3(512), 0, stream>>>(u, r0, W, Bm, tau, ds, out,
                                                   arr, xcc_arr, sflags, zreg, obs);
}